// Round 1
// baseline (305.745 us; speedup 1.0000x reference)
//
#include <hip/hip_runtime.h>

typedef short bf16x8 __attribute__((ext_vector_type(8)));
typedef float f32x4 __attribute__((ext_vector_type(4)));
typedef unsigned int u32;

#define MFMA16 __builtin_amdgcn_mfma_f32_16x16x32_bf16

#define SCALE 0.17677669529663687f  // 1/sqrt(32)

// ws layout (bytes):
//   wqkv  bf16 [576][192]          @ 0        (221184)
//   wproj bf16 [192][192]          @ 221184   (73728)
//   biasar f32 [6][16][64][4]      @ 294912   (98304)
//   bq    f32  [576]               @ 393216   (2304)

__device__ __forceinline__ unsigned short f2b(float x) {
  u32 u = __float_as_uint(x);
  u = (u + 0x7FFFu + ((u >> 16) & 1u)) >> 16;
  return (unsigned short)u;
}
__device__ __forceinline__ u32 pk2(float a, float b) {
  u32 ua = __float_as_uint(a), ub = __float_as_uint(b);
  ua = (ua + 0x7FFFu + ((ua >> 16) & 1u)) >> 16;
  ub = (ub + 0x7FFFu + ((ub >> 16) & 1u)) >> 16;
  return (ua & 0xFFFFu) | (ub << 16);
}

__global__ void prep_kernel(const float* __restrict__ qkv_w, const float* __restrict__ qkv_b,
                            const float* __restrict__ proj_w, const float* __restrict__ rpb,
                            unsigned short* __restrict__ wqkv, unsigned short* __restrict__ wproj,
                            float* __restrict__ biasar, float* __restrict__ bq) {
  int i0 = blockIdx.x * blockDim.x + threadIdx.x;
  int stride = gridDim.x * blockDim.x;
  for (int i = i0; i < 576 * 192; i += stride) {
    float v = qkv_w[i];
    if (i < 192 * 192) v *= SCALE;  // q rows are f < 192
    wqkv[i] = f2b(v);
  }
  for (int i = i0; i < 192 * 192; i += stride) wproj[i] = f2b(proj_w[i]);
  for (int i = i0; i < 576; i += stride) {
    float v = qkv_b[i];
    if (i < 192) v *= SCALE;
    bq[i] = v;
  }
  // bias pre-arranged in S^T C-fragment layout:
  // frag id = mt*4+nt; value at (lane,r): m = mt*16 + (lane>>4)*4 + r ; n = nt*16 + (lane&15)
  for (int i = i0; i < 6 * 16 * 64 * 4; i += stride) {
    int r = i & 3;
    int lane = (i >> 2) & 63;
    int fid = (i >> 8) & 15;
    int h = i >> 12;
    int mt = fid >> 2, nt = fid & 3;
    int m = mt * 16 + (lane >> 4) * 4 + r;
    int n = nt * 16 + (lane & 15);
    int idx = ((n >> 3) - (m >> 3) + 7) * 15 + ((n & 7) - (m & 7) + 7);
    biasar[i] = rpb[idx * 6 + h];
  }
}

// One block = one window. 6 waves, wave w = head w.
// LDS: [0,13312)        x chunk, bf16 [64][104] (rows 208 B)
//      [13312,44032)    per-wave scratch, 5120 B each (Q/K/P: [64][40] rows 80B; V: [32][72] rows 144B)
//      after attention: Os bf16 [64][200] (rows 400 B) overlays [0,25600)
__global__ void __launch_bounds__(384) win_attn(
    const float* __restrict__ x, const unsigned short* __restrict__ wqkv,
    const unsigned short* __restrict__ wproj, const float* __restrict__ biasar,
    const float* __restrict__ bq, const float* __restrict__ proj_b, float* __restrict__ out) {
  __shared__ __align__(16) char smem[44032];
  const int b = blockIdx.x;
  const int tid = threadIdx.x;
  const int w = tid >> 6;       // wave = head
  const int lane = tid & 63;
  const int g = lane >> 4;      // 16-lane group
  const int c = lane & 15;
  char* scr = smem + 13312 + w * 5120;

  f32x4 accQ[2][4], accK[2][4], accV[4][2];
#pragma unroll
  for (int a = 0; a < 2; ++a)
#pragma unroll
    for (int t = 0; t < 4; ++t) {
      accQ[a][t] = (f32x4)0.0f;
      accK[a][t] = (f32x4)0.0f;
      accV[t][a] = (f32x4)0.0f;
    }

  // ---------- Phase A: QKV projection (K-chunked x staging) ----------
  for (int ck = 0; ck < 2; ++ck) {
    {
      const float* xb = x + (size_t)b * 12288 + ck * 96;
#pragma unroll
      for (int it = 0; it < 4; ++it) {
        int idx = tid + it * 384;       // float4 index in [0,1536)
        int tok = idx / 24, c4 = idx % 24;
        float4 v = *(const float4*)(xb + tok * 192 + c4 * 4);
        *(uint2*)(smem + tok * 208 + c4 * 8) = make_uint2(pk2(v.x, v.y), pk2(v.z, v.w));
      }
    }
    __syncthreads();
#pragma unroll
    for (int kt = 0; kt < 3; ++kt) {
      int cb = ck * 96 + kt * 32 + 8 * g;
      bf16x8 wqf[2], wkf[2], wvf[2];
#pragma unroll
      for (int dt = 0; dt < 2; ++dt) {
        int fr = w * 32 + dt * 16 + c;
        wqf[dt] = *(const bf16x8*)(wqkv + (size_t)fr * 192 + cb);
        wkf[dt] = *(const bf16x8*)(wqkv + (size_t)(192 + fr) * 192 + cb);
        wvf[dt] = *(const bf16x8*)(wqkv + (size_t)(384 + fr) * 192 + cb);
      }
#pragma unroll
      for (int tt = 0; tt < 4; ++tt) {
        bf16x8 xf = *(const bf16x8*)(smem + (tt * 16 + c) * 208 + (kt * 32 + 8 * g) * 2);
#pragma unroll
        for (int dt = 0; dt < 2; ++dt) {
          accQ[dt][tt] = MFMA16(wqf[dt], xf, accQ[dt][tt], 0, 0, 0);  // C = Q^T [d][tok]
          accK[dt][tt] = MFMA16(wkf[dt], xf, accK[dt][tt], 0, 0, 0);  // C = K^T [d][tok]
          accV[tt][dt] = MFMA16(xf, wvf[dt], accV[tt][dt], 0, 0, 0);  // C = V   [tok][d]
        }
      }
    }
    __syncthreads();
  }

  // qkv biases (q/k pre-scaled in prep)
#pragma unroll
  for (int dt = 0; dt < 2; ++dt)
#pragma unroll
    for (int r = 0; r < 4; ++r) {
      float bqv = bq[w * 32 + dt * 16 + 4 * g + r];
      float bkv = bq[192 + w * 32 + dt * 16 + 4 * g + r];
#pragma unroll
      for (int tt = 0; tt < 4; ++tt) {
        accQ[dt][tt][r] += bqv;
        accK[dt][tt][r] += bkv;
      }
    }
#pragma unroll
  for (int dt = 0; dt < 2; ++dt) {
    float bvv = bq[384 + w * 32 + dt * 16 + c];
#pragma unroll
    for (int mt = 0; mt < 4; ++mt)
#pragma unroll
      for (int r = 0; r < 4; ++r) accV[mt][dt][r] += bvv;
  }

  // ---------- C-layout -> operand-layout bounces (wave-private scratch) ----------
  bf16x8 qb[4], ka[4], va[2][2];
  // Q: write Q^T value(d,n) at scr[n*80 + d*2]; read B-frag (n=l&15, d=8g..8g+7)
#pragma unroll
  for (int dt = 0; dt < 2; ++dt)
#pragma unroll
    for (int nt = 0; nt < 4; ++nt)
      *(uint2*)(scr + (nt * 16 + c) * 80 + (dt * 16 + 4 * g) * 2) =
          make_uint2(pk2(accQ[dt][nt][0], accQ[dt][nt][1]), pk2(accQ[dt][nt][2], accQ[dt][nt][3]));
#pragma unroll
  for (int nt = 0; nt < 4; ++nt) qb[nt] = *(const bf16x8*)(scr + (nt * 16 + c) * 80 + 16 * g);
  // K: same pattern -> A-frags
#pragma unroll
  for (int dt = 0; dt < 2; ++dt)
#pragma unroll
    for (int mt = 0; mt < 4; ++mt)
      *(uint2*)(scr + (mt * 16 + c) * 80 + (dt * 16 + 4 * g) * 2) =
          make_uint2(pk2(accK[dt][mt][0], accK[dt][mt][1]), pk2(accK[dt][mt][2], accK[dt][mt][3]));
#pragma unroll
  for (int mt = 0; mt < 4; ++mt) ka[mt] = *(const bf16x8*)(scr + (mt * 16 + c) * 80 + 16 * g);
  // V: write value(m,d) at scr[d*144 + m*2]; read A-frags of V^T (d=l&15, m=kt*32+8g..)
#pragma unroll
  for (int mt = 0; mt < 4; ++mt)
#pragma unroll
    for (int dt = 0; dt < 2; ++dt)
      *(uint2*)(scr + (dt * 16 + c) * 144 + (mt * 16 + 4 * g) * 2) =
          make_uint2(pk2(accV[mt][dt][0], accV[mt][dt][1]), pk2(accV[mt][dt][2], accV[mt][dt][3]));
#pragma unroll
  for (int dt = 0; dt < 2; ++dt)
#pragma unroll
    for (int kt = 0; kt < 2; ++kt)
      va[dt][kt] = *(const bf16x8*)(scr + (dt * 16 + c) * 144 + (kt * 32 + 8 * g) * 2);

  // ---------- Phase B: S^T = K @ Q^T  (+ bias) ----------
  f32x4 s[4][4];
#pragma unroll
  for (int mt = 0; mt < 4; ++mt)
#pragma unroll
    for (int nt = 0; nt < 4; ++nt) s[mt][nt] = (f32x4)0.0f;
#pragma unroll
  for (int mt = 0; mt < 4; ++mt)
#pragma unroll
    for (int nt = 0; nt < 4; ++nt) s[mt][nt] = MFMA16(ka[mt], qb[nt], s[mt][nt], 0, 0, 0);
  const f32x4* bias4 = (const f32x4*)biasar;
#pragma unroll
  for (int mt = 0; mt < 4; ++mt)
#pragma unroll
    for (int nt = 0; nt < 4; ++nt) s[mt][nt] += bias4[(w * 16 + mt * 4 + nt) * 64 + lane];

  // ---------- Phase C: softmax over m (rows at fixed n = l&15) ----------
  float linv[4];
#pragma unroll
  for (int nt = 0; nt < 4; ++nt) {
    float mx = -1e30f;
#pragma unroll
    for (int mt = 0; mt < 4; ++mt)
#pragma unroll
      for (int r = 0; r < 4; ++r) mx = fmaxf(mx, s[mt][nt][r]);
    mx = fmaxf(mx, __shfl_xor(mx, 16));
    mx = fmaxf(mx, __shfl_xor(mx, 32));
    float sum = 0.0f;
#pragma unroll
    for (int mt = 0; mt < 4; ++mt)
#pragma unroll
      for (int r = 0; r < 4; ++r) {
        float e = __expf(s[mt][nt][r] - mx);
        s[mt][nt][r] = e;
        sum += e;
      }
    sum += __shfl_xor(sum, 16);
    sum += __shfl_xor(sum, 32);
    linv[nt] = 1.0f / sum;
  }

  // ---------- Phase D: O^T = V^T @ P^T (P bounced in two m-halves) ----------
  f32x4 o[2][4];
#pragma unroll
  for (int dt = 0; dt < 2; ++dt)
#pragma unroll
    for (int nt = 0; nt < 4; ++nt) o[dt][nt] = (f32x4)0.0f;
#pragma unroll
  for (int half = 0; half < 2; ++half) {
#pragma unroll
    for (int mt2 = 0; mt2 < 2; ++mt2) {
      int mt = half * 2 + mt2;
#pragma unroll
      for (int nt = 0; nt < 4; ++nt)
        *(uint2*)(scr + (nt * 16 + c) * 80 + (mt2 * 16 + 4 * g) * 2) =
            make_uint2(pk2(s[mt][nt][0], s[mt][nt][1]), pk2(s[mt][nt][2], s[mt][nt][3]));
    }
#pragma unroll
    for (int nt = 0; nt < 4; ++nt) {
      bf16x8 pb = *(const bf16x8*)(scr + (nt * 16 + c) * 80 + 16 * g);
#pragma unroll
      for (int dt = 0; dt < 2; ++dt) o[dt][nt] = MFMA16(va[dt][half], pb, o[dt][nt], 0, 0, 0);
    }
  }
#pragma unroll
  for (int dt = 0; dt < 2; ++dt)
#pragma unroll
    for (int nt = 0; nt < 4; ++nt)
#pragma unroll
      for (int r = 0; r < 4; ++r) o[dt][nt][r] *= linv[nt];

  // ---------- Os stage (token-major [64][200] bf16, overlays x/scratch) ----------
  __syncthreads();  // everyone done with scratch + x chunk
#pragma unroll
  for (int dt = 0; dt < 2; ++dt)
#pragma unroll
    for (int nt = 0; nt < 4; ++nt)
      *(uint2*)(smem + (nt * 16 + c) * 400 + (w * 32 + dt * 16 + 4 * g) * 2) =
          make_uint2(pk2(o[dt][nt][0], o[dt][nt][1]), pk2(o[dt][nt][2], o[dt][nt][3]));
  __syncthreads();

  // ---------- Phase E: out = Os @ proj_w^T + proj_b (wave w -> 32 output cols) ----------
  f32x4 accP[4][2];
#pragma unroll
  for (int mt = 0; mt < 4; ++mt)
#pragma unroll
    for (int ft = 0; ft < 2; ++ft) accP[mt][ft] = (f32x4)0.0f;
#pragma unroll
  for (int kt = 0; kt < 6; ++kt) {
    bf16x8 wp[2];
#pragma unroll
    for (int ft = 0; ft < 2; ++ft)
      wp[ft] = *(const bf16x8*)(wproj + (size_t)(w * 32 + ft * 16 + c) * 192 + kt * 32 + 8 * g);
#pragma unroll
    for (int mt = 0; mt < 4; ++mt) {
      bf16x8 of = *(const bf16x8*)(smem + (mt * 16 + c) * 400 + (kt * 32 + 8 * g) * 2);
#pragma unroll
      for (int ft = 0; ft < 2; ++ft) accP[mt][ft] = MFMA16(of, wp[ft], accP[mt][ft], 0, 0, 0);
    }
  }
  float pb0 = proj_b[w * 32 + c];
  float pb1 = proj_b[w * 32 + 16 + c];
  float* outb = out + (size_t)b * 12288;
#pragma unroll
  for (int mt = 0; mt < 4; ++mt)
#pragma unroll
    for (int ft = 0; ft < 2; ++ft) {
      float pbv = ft ? pb1 : pb0;
#pragma unroll
      for (int r = 0; r < 4; ++r)
        outb[(mt * 16 + 4 * g + r) * 192 + w * 32 + ft * 16 + c] = accP[mt][ft][r] + pbv;
    }
}

extern "C" void kernel_launch(void* const* d_in, const int* in_sizes, int n_in,
                              void* d_out, int out_size, void* d_ws, size_t ws_size,
                              hipStream_t stream) {
  const float* x = (const float*)d_in[0];
  const float* qkv_w = (const float*)d_in[1];
  const float* qkv_b = (const float*)d_in[2];
  const float* proj_w = (const float*)d_in[3];
  const float* proj_b = (const float*)d_in[4];
  const float* rpb = (const float*)d_in[5];
  char* ws = (char*)d_ws;
  unsigned short* wqkv = (unsigned short*)ws;
  unsigned short* wproj = (unsigned short*)(ws + 221184);
  float* biasar = (float*)(ws + 294912);
  float* bqv = (float*)(ws + 393216);

  prep_kernel<<<432, 256, 0, stream>>>(qkv_w, qkv_b, proj_w, rpb, wqkv, wproj, biasar, bqv);
  win_attn<<<4096, 384, 0, stream>>>(x, wqkv, wproj, biasar, bqv, proj_b, (float*)d_out);
}

// Round 2
// 291.469 us; speedup vs baseline: 1.0490x; 1.0490x over previous
//
#include <hip/hip_runtime.h>
#include <hip/hip_bf16.h>

typedef short bf16x8 __attribute__((ext_vector_type(8)));
typedef float f32x4 __attribute__((ext_vector_type(4)));
typedef unsigned int u32;

#define MFMA16 __builtin_amdgcn_mfma_f32_16x16x32_bf16
#define SCALE 0.17677669529663687f  // 1/sqrt(32)

// ws layout (bytes):
//   wqkv  bf16 [576][192]          @ 0        (221184)
//   wproj bf16 [192][192]          @ 221184   (73728)
//   biasar f32 [6][16][64][4]      @ 294912   (98304)
//   bq    f32  [576]               @ 393216   (2304)

__device__ __forceinline__ unsigned short f2b(float x) {
  u32 u = __float_as_uint(x);
  u = (u + 0x7FFFu + ((u >> 16) & 1u)) >> 16;
  return (unsigned short)u;
}
__device__ __forceinline__ u32 pk2(float a, float b) {
  __hip_bfloat162 h = __float22bfloat162_rn(float2{a, b});
  return *(u32*)&h;
}
__device__ __forceinline__ uint2 pk4(f32x4 v) {
  return make_uint2(pk2(v[0], v[1]), pk2(v[2], v[3]));
}

__global__ void prep_kernel(const float* __restrict__ qkv_w, const float* __restrict__ qkv_b,
                            const float* __restrict__ proj_w, const float* __restrict__ rpb,
                            unsigned short* __restrict__ wqkv, unsigned short* __restrict__ wproj,
                            float* __restrict__ biasar, float* __restrict__ bq) {
  int i0 = blockIdx.x * blockDim.x + threadIdx.x;
  int stride = gridDim.x * blockDim.x;
  for (int i = i0; i < 576 * 192; i += stride) {
    float v = qkv_w[i];
    if (i < 192 * 192) v *= SCALE;  // q rows are f < 192
    wqkv[i] = f2b(v);
  }
  for (int i = i0; i < 192 * 192; i += stride) wproj[i] = f2b(proj_w[i]);
  for (int i = i0; i < 576; i += stride) {
    float v = qkv_b[i];
    if (i < 192) v *= SCALE;
    bq[i] = v;
  }
  // bias pre-arranged in S^T C-fragment layout:
  // frag id = mt*4+nt; value at (lane,r): m = mt*16 + (lane>>4)*4 + r ; n = nt*16 + (lane&15)
  for (int i = i0; i < 6 * 16 * 64 * 4; i += stride) {
    int r = i & 3;
    int lane = (i >> 2) & 63;
    int fid = (i >> 8) & 15;
    int h = i >> 12;
    int mt = fid >> 2, nt = fid & 3;
    int m = mt * 16 + (lane >> 4) * 4 + r;
    int n = nt * 16 + (lane & 15);
    int idx = ((n >> 3) - (m >> 3) + 7) * 15 + ((n & 7) - (m & 7) + 7);
    biasar[i] = rpb[idx * 6 + h];
  }
}

// One block = one window. 6 waves, wave w = head w.
// LDS (49152 B total -> 3 blocks/CU):
//   [0, 24576)       xs: x bf16 [64 tok][384B rows], 16B slots XOR-swizzled by (row&7)
//                    (after attention: Os bf16, same geometry, overlays xs)
//   [24576, 49152)   per-wave scratch, 4096 B each:
//                    Q/K/P bounce: [64 rows][64B] slots^(row&3); V bounce: [32 rows][128B] slots^(row&7)
__global__ void __launch_bounds__(384, 5) win_attn(
    const float* __restrict__ x, const unsigned short* __restrict__ wqkv,
    const unsigned short* __restrict__ wproj, const float* __restrict__ biasar,
    const float* __restrict__ bq, const float* __restrict__ proj_b, float* __restrict__ out) {
  __shared__ __align__(16) char smem[49152];
  const int b = blockIdx.x;
  const int tid = threadIdx.x;
  const int w = tid >> 6;       // wave = head
  const int lane = tid & 63;
  const int g = lane >> 4;      // 16-lane group
  const int c = lane & 15;
  char* xs = smem;
  char* scr = smem + 24576 + w * 4096;

  // ---------- stage full x -> bf16 swizzled LDS ----------
  {
    const float* xb = x + (size_t)b * 12288;
#pragma unroll
    for (int it = 0; it < 8; ++it) {
      int idx = tid + it * 384;           // float4 index in [0,3072)
      int tok = idx / 48, c4 = idx % 48;
      float4 v = *(const float4*)(xb + tok * 192 + c4 * 4);
      *(uint2*)(xs + tok * 384 + (((c4 >> 1) ^ (tok & 7)) << 4) + (c4 & 1) * 8) =
          make_uint2(pk2(v.x, v.y), pk2(v.z, v.w));
    }
  }
  __syncthreads();

#define XFRAG(tt, kt) \
  (*(const bf16x8*)(xs + ((tt) * 16 + c) * 384 + ((((kt) * 4 + g) ^ (c & 7)) << 4)))

  // ---------- Q pass ----------
  bf16x8 qb[4];
  {
    f32x4 acc[2][4];
#pragma unroll
    for (int dt = 0; dt < 2; ++dt)
#pragma unroll
      for (int tt = 0; tt < 4; ++tt) acc[dt][tt] = (f32x4)0.0f;
#pragma unroll
    for (int kt = 0; kt < 6; ++kt) {
      bf16x8 wf[2];
#pragma unroll
      for (int dt = 0; dt < 2; ++dt)
        wf[dt] = *(const bf16x8*)(wqkv + (size_t)(w * 32 + dt * 16 + c) * 192 + kt * 32 + 8 * g);
#pragma unroll
      for (int tt = 0; tt < 4; ++tt) {
        bf16x8 xf = XFRAG(tt, kt);
#pragma unroll
        for (int dt = 0; dt < 2; ++dt) acc[dt][tt] = MFMA16(wf[dt], xf, acc[dt][tt], 0, 0, 0);
      }
    }
#pragma unroll
    for (int dt = 0; dt < 2; ++dt)
#pragma unroll
      for (int r = 0; r < 4; ++r) {
        float bv = bq[w * 32 + dt * 16 + 4 * g + r];
#pragma unroll
        for (int tt = 0; tt < 4; ++tt) acc[dt][tt][r] += bv;
      }
#pragma unroll
    for (int dt = 0; dt < 2; ++dt)
#pragma unroll
      for (int nt = 0; nt < 4; ++nt)
        *(uint2*)(scr + (nt * 16 + c) * 64 + (((dt * 2 + (g >> 1)) ^ (c & 3)) << 4) + (g & 1) * 8) =
            pk4(acc[dt][nt]);
#pragma unroll
    for (int nt = 0; nt < 4; ++nt)
      qb[nt] = *(const bf16x8*)(scr + (nt * 16 + c) * 64 + ((g ^ (c & 3)) << 4));
  }

  // ---------- K pass ----------
  bf16x8 ka[4];
  {
    f32x4 acc[2][4];
#pragma unroll
    for (int dt = 0; dt < 2; ++dt)
#pragma unroll
      for (int tt = 0; tt < 4; ++tt) acc[dt][tt] = (f32x4)0.0f;
#pragma unroll
    for (int kt = 0; kt < 6; ++kt) {
      bf16x8 wf[2];
#pragma unroll
      for (int dt = 0; dt < 2; ++dt)
        wf[dt] = *(const bf16x8*)(wqkv + (size_t)(192 + w * 32 + dt * 16 + c) * 192 + kt * 32 + 8 * g);
#pragma unroll
      for (int tt = 0; tt < 4; ++tt) {
        bf16x8 xf = XFRAG(tt, kt);
#pragma unroll
        for (int dt = 0; dt < 2; ++dt) acc[dt][tt] = MFMA16(wf[dt], xf, acc[dt][tt], 0, 0, 0);
      }
    }
#pragma unroll
    for (int dt = 0; dt < 2; ++dt)
#pragma unroll
      for (int r = 0; r < 4; ++r) {
        float bv = bq[192 + w * 32 + dt * 16 + 4 * g + r];
#pragma unroll
        for (int tt = 0; tt < 4; ++tt) acc[dt][tt][r] += bv;
      }
#pragma unroll
    for (int dt = 0; dt < 2; ++dt)
#pragma unroll
      for (int mt = 0; mt < 4; ++mt)
        *(uint2*)(scr + (mt * 16 + c) * 64 + (((dt * 2 + (g >> 1)) ^ (c & 3)) << 4) + (g & 1) * 8) =
            pk4(acc[dt][mt]);
#pragma unroll
    for (int mt = 0; mt < 4; ++mt)
      ka[mt] = *(const bf16x8*)(scr + (mt * 16 + c) * 64 + ((g ^ (c & 3)) << 4));
  }

  // ---------- S in two n-halves: bias, softmax, pack P frags ----------
  bf16x8 pbf[2][4];
  float linv[4];
  const f32x4* bias4 = (const f32x4*)biasar;
#pragma unroll
  for (int h = 0; h < 2; ++h) {
    f32x4 s[4][2];
#pragma unroll
    for (int mt = 0; mt < 4; ++mt)
#pragma unroll
      for (int n2 = 0; n2 < 2; ++n2) {
        int nt = h * 2 + n2;
        f32x4 t = MFMA16(ka[mt], qb[nt], (f32x4)0.0f, 0, 0, 0);
        s[mt][n2] = t + bias4[(w * 16 + mt * 4 + nt) * 64 + lane];
      }
#pragma unroll
    for (int n2 = 0; n2 < 2; ++n2) {
      int nt = h * 2 + n2;
      float mx = -1e30f;
#pragma unroll
      for (int mt = 0; mt < 4; ++mt)
#pragma unroll
        for (int r = 0; r < 4; ++r) mx = fmaxf(mx, s[mt][n2][r]);
      mx = fmaxf(mx, __shfl_xor(mx, 16));
      mx = fmaxf(mx, __shfl_xor(mx, 32));
      float sum = 0.0f;
#pragma unroll
      for (int mt = 0; mt < 4; ++mt)
#pragma unroll
        for (int r = 0; r < 4; ++r) {
          float e = __expf(s[mt][n2][r] - mx);
          s[mt][n2][r] = e;
          sum += e;
        }
      sum += __shfl_xor(sum, 16);
      sum += __shfl_xor(sum, 32);
      linv[nt] = 1.0f / sum;
    }
    // bounce P^T C-frags -> B-frags (rows: mh*32 + n2*16 + c, so the two m-halves don't alias)
#pragma unroll
    for (int mh = 0; mh < 2; ++mh)
#pragma unroll
      for (int mt2 = 0; mt2 < 2; ++mt2)
#pragma unroll
        for (int n2 = 0; n2 < 2; ++n2)
          *(uint2*)(scr + (mh * 32 + n2 * 16 + c) * 64 +
                    (((mt2 * 2 + (g >> 1)) ^ (c & 3)) << 4) + (g & 1) * 8) =
              pk4(s[mh * 2 + mt2][n2]);
#pragma unroll
    for (int mh = 0; mh < 2; ++mh)
#pragma unroll
      for (int n2 = 0; n2 < 2; ++n2)
        pbf[mh][h * 2 + n2] =
            *(const bf16x8*)(scr + (mh * 32 + n2 * 16 + c) * 64 + ((g ^ (c & 3)) << 4));
  }

  // ---------- V pass ----------
  bf16x8 va[2][2];
  {
    f32x4 acc[4][2];
#pragma unroll
    for (int mt = 0; mt < 4; ++mt)
#pragma unroll
      for (int dt = 0; dt < 2; ++dt) acc[mt][dt] = (f32x4)0.0f;
#pragma unroll
    for (int kt = 0; kt < 6; ++kt) {
      bf16x8 wf[2];
#pragma unroll
      for (int dt = 0; dt < 2; ++dt)
        wf[dt] = *(const bf16x8*)(wqkv + (size_t)(384 + w * 32 + dt * 16 + c) * 192 + kt * 32 + 8 * g);
#pragma unroll
      for (int tt = 0; tt < 4; ++tt) {
        bf16x8 xf = XFRAG(tt, kt);
#pragma unroll
        for (int dt = 0; dt < 2; ++dt) acc[tt][dt] = MFMA16(xf, wf[dt], acc[tt][dt], 0, 0, 0);
      }
    }
#pragma unroll
    for (int dt = 0; dt < 2; ++dt) {
      float bv = bq[384 + w * 32 + dt * 16 + c];
#pragma unroll
      for (int mt = 0; mt < 4; ++mt)
#pragma unroll
        for (int r = 0; r < 4; ++r) acc[mt][dt][r] += bv;
    }
    // bounce V (C: m=tok rows) -> V^T A-frags ([32 d rows][128B], slots^(c&7))
#pragma unroll
    for (int mt = 0; mt < 4; ++mt)
#pragma unroll
      for (int dt = 0; dt < 2; ++dt)
        *(uint2*)(scr + (dt * 16 + c) * 128 + (((mt * 2 + (g >> 1)) ^ (c & 7)) << 4) + (g & 1) * 8) =
            pk4(acc[mt][dt]);
#pragma unroll
    for (int dt = 0; dt < 2; ++dt)
#pragma unroll
      for (int kh = 0; kh < 2; ++kh)
        va[dt][kh] = *(const bf16x8*)(scr + (dt * 16 + c) * 128 + (((kh * 4 + g) ^ (c & 7)) << 4));
  }

  // ---------- O^T = V^T @ P^T ----------
  f32x4 o[2][4];
#pragma unroll
  for (int dt = 0; dt < 2; ++dt)
#pragma unroll
    for (int nt = 0; nt < 4; ++nt) o[dt][nt] = (f32x4)0.0f;
#pragma unroll
  for (int mh = 0; mh < 2; ++mh)
#pragma unroll
    for (int nt = 0; nt < 4; ++nt)
#pragma unroll
      for (int dt = 0; dt < 2; ++dt) o[dt][nt] = MFMA16(va[dt][mh], pbf[mh][nt], o[dt][nt], 0, 0, 0);
#pragma unroll
  for (int dt = 0; dt < 2; ++dt)
#pragma unroll
    for (int nt = 0; nt < 4; ++nt)
#pragma unroll
      for (int r = 0; r < 4; ++r) o[dt][nt][r] *= linv[nt];

  // ---------- Os stage (token rows, overlays xs) ----------
  __syncthreads();
#pragma unroll
  for (int dt = 0; dt < 2; ++dt)
#pragma unroll
    for (int nt = 0; nt < 4; ++nt)
      *(uint2*)(xs + (nt * 16 + c) * 384 + (((w * 4 + dt * 2 + (g >> 1)) ^ (c & 7)) << 4) +
                (g & 1) * 8) = pk4(o[dt][nt]);
  __syncthreads();

  // ---------- proj: out = Os @ proj_w^T + proj_b ----------
  f32x4 accP[4][2];
#pragma unroll
  for (int mt = 0; mt < 4; ++mt)
#pragma unroll
    for (int ft = 0; ft < 2; ++ft) accP[mt][ft] = (f32x4)0.0f;
#pragma unroll
  for (int kt = 0; kt < 6; ++kt) {
    bf16x8 wp[2];
#pragma unroll
    for (int ft = 0; ft < 2; ++ft)
      wp[ft] = *(const bf16x8*)(wproj + (size_t)(w * 32 + ft * 16 + c) * 192 + kt * 32 + 8 * g);
#pragma unroll
    for (int mt = 0; mt < 4; ++mt) {
      bf16x8 of = *(const bf16x8*)(xs + (mt * 16 + c) * 384 + (((kt * 4 + g) ^ (c & 7)) << 4));
#pragma unroll
      for (int ft = 0; ft < 2; ++ft) accP[mt][ft] = MFMA16(of, wp[ft], accP[mt][ft], 0, 0, 0);
    }
  }
  float pb0 = proj_b[w * 32 + c];
  float pb1 = proj_b[w * 32 + 16 + c];
  float* outb = out + (size_t)b * 12288;
#pragma unroll
  for (int mt = 0; mt < 4; ++mt)
#pragma unroll
    for (int ft = 0; ft < 2; ++ft) {
      float pbv = ft ? pb1 : pb0;
#pragma unroll
      for (int r = 0; r < 4; ++r)
        outb[(mt * 16 + 4 * g + r) * 192 + w * 32 + ft * 16 + c] = accP[mt][ft][r] + pbv;
    }
}

extern "C" void kernel_launch(void* const* d_in, const int* in_sizes, int n_in,
                              void* d_out, int out_size, void* d_ws, size_t ws_size,
                              hipStream_t stream) {
  const float* x = (const float*)d_in[0];
  const float* qkv_w = (const float*)d_in[1];
  const float* qkv_b = (const float*)d_in[2];
  const float* proj_w = (const float*)d_in[3];
  const float* proj_b = (const float*)d_in[4];
  const float* rpb = (const float*)d_in[5];
  char* ws = (char*)d_ws;
  unsigned short* wqkv = (unsigned short*)ws;
  unsigned short* wproj = (unsigned short*)(ws + 221184);
  float* biasar = (float*)(ws + 294912);
  float* bqv = (float*)(ws + 393216);

  prep_kernel<<<432, 256, 0, stream>>>(qkv_w, qkv_b, proj_w, rpb, wqkv, wproj, biasar, bqv);
  win_attn<<<4096, 384, 0, stream>>>(x, wqkv, wproj, biasar, bqv, proj_b, (float*)d_out);
}